// Round 12
// baseline (937.760 us; speedup 1.0000x reference)
//
#include <hip/hip_runtime.h>

typedef __attribute__((ext_vector_type(8))) short bf16x8;
typedef __attribute__((ext_vector_type(4))) float f32x4;
typedef __attribute__((ext_vector_type(2))) float f32x2;
typedef __attribute__((ext_vector_type(4))) unsigned int u32x4;

#define SDIM 2048
#define DDIM 64
#define NBH  32
#define KHALF 1024

__device__ __forceinline__ unsigned short f2bf(float f) {
    union { float f; unsigned int u; } x;
    x.f = f;
    unsigned int u = x.u;
    u += 0x7FFFu + ((u >> 16) & 1u);  // round-to-nearest-even
    return (unsigned short)(u >> 16);
}

__device__ __forceinline__ unsigned int packbf(float a, float b) {
    return (unsigned int)f2bf(a) | ((unsigned int)f2bf(b) << 16);
}

__device__ __forceinline__ float asf(unsigned int u) {
    union { unsigned int u; float f; } x; x.u = u; return x.f;
}

// transpose [bh][R][C] f32 -> [bh][C][R] bf16(ushort), 64x64 tiles via LDS
__global__ __launch_bounds__(256) void transpose_cvt(
    const float* __restrict__ in, unsigned short* __restrict__ out,
    int R, int C)
{
    __shared__ float tile[64][65];
    const int bh = blockIdx.z;
    const int ct = blockIdx.x * 64;
    const int rt = blockIdx.y * 64;
    const float* src = in + (size_t)bh * R * C;
    unsigned short* dst = out + (size_t)bh * R * C;
    const int r = threadIdx.x >> 2;   // 0..63
    const int p = threadIdx.x & 3;    // 0..3
    const float* sp = src + (size_t)(rt + r) * C + ct + p * 16;
#pragma unroll
    for (int j = 0; j < 4; ++j) {
        f32x4 a = *(const f32x4*)(sp + j * 4);
        tile[r][p*16 + j*4 + 0] = a.x;
        tile[r][p*16 + j*4 + 1] = a.y;
        tile[r][p*16 + j*4 + 2] = a.z;
        tile[r][p*16 + j*4 + 3] = a.w;
    }
    __syncthreads();
    u32x4 w0, w1;
    w0.x = packbf(tile[p*16+ 0][r], tile[p*16+ 1][r]);
    w0.y = packbf(tile[p*16+ 2][r], tile[p*16+ 3][r]);
    w0.z = packbf(tile[p*16+ 4][r], tile[p*16+ 5][r]);
    w0.w = packbf(tile[p*16+ 6][r], tile[p*16+ 7][r]);
    w1.x = packbf(tile[p*16+ 8][r], tile[p*16+ 9][r]);
    w1.y = packbf(tile[p*16+10][r], tile[p*16+11][r]);
    w1.z = packbf(tile[p*16+12][r], tile[p*16+13][r]);
    w1.w = packbf(tile[p*16+14][r], tile[p*16+15][r]);
    unsigned short* dp = dst + (size_t)(ct + r) * R + rt + p * 16;
    *(u32x4*)dp = w0;
    *(u32x4*)(dp + 8) = w1;
}

// Split-K fused attention partial (no-max softmax). Block = (qt, kh, bh):
// 64 Q rows, one 1024-wide K-half (16 iterations of 64). Writes its scores
// half directly; writes UN-normalized partial O + partial l to ws (combined
// by combine_halves). K tile single-buffered in LDS (8KB) with raw
// s_barriers (no vmcnt drain); S/P exchange + epilogue via s_lds, all
// intra-wave. prev prefetched 1 tile ahead; V/K issued at iteration top.
__global__ __launch_bounds__(256, 6) void attn_partial(
    const float* __restrict__ q, const float* __restrict__ prev,
    const unsigned short* __restrict__ kT, const unsigned short* __restrict__ vT,
    float* __restrict__ Opart, float* __restrict__ lpart,
    float* __restrict__ scores)
{
    const int qt   = blockIdx.x;          // 64-row Q tile index
    const int kh   = blockIdx.y;          // K half
    const int bh   = blockIdx.z;
    const int tid  = threadIdx.x;
    const int wave = tid >> 6;
    const int lane = tid & 63;
    const int ln   = lane & 15;           // 0..15
    const int lg   = lane >> 4;           // 0..3

    __shared__ float s_lds[64][68];            // S exchange + packed-P (reused)
    __shared__ unsigned short ksmem[4096];     // K tile single buffer (swizzled)

    // ---- Q fragments (A operand: row = ln, k(d) = kc*32 + lg*8 + j) ----
    const int qrow_frag = qt * 64 + wave * 16 + ln;
    bf16x8 qf[2];
    {
        const float* qp = q + ((size_t)bh * SDIM + qrow_frag) * DDIM + lg * 8;
#pragma unroll
        for (int kc = 0; kc < 2; ++kc) {
            f32x4 a = *(const f32x4*)(qp + kc * 32);
            f32x4 b = *(const f32x4*)(qp + kc * 32 + 4);
            bf16x8 f;
            f[0] = (short)f2bf(a.x); f[1] = (short)f2bf(a.y);
            f[2] = (short)f2bf(a.z); f[3] = (short)f2bf(a.w);
            f[4] = (short)f2bf(b.x); f[5] = (short)f2bf(b.y);
            f[6] = (short)f2bf(b.z); f[7] = (short)f2bf(b.w);
            qf[kc] = f;
        }
    }

    const unsigned short* kbase = kT + ((size_t)bh * SDIM + kh * KHALF) * DDIM;
    const unsigned short* vbase = vT + ((size_t)bh * DDIM + ln) * SDIM + kh * KHALF + lg * 8;

    // ---- row-layout identity: 8 lanes per row, 2 row groups ----
    const int rsub = lane >> 3;           // 0..7
    const int cq   = lane & 7;            // col octet: floats cq*4..cq*4+3
    const int rl0  = wave * 16 + rsub;    // block-local rows
    const int rl1  = rl0 + 8;
    const size_t grow0 = ((size_t)bh * SDIM + qt * 64 + rl0) * SDIM + kh * KHALF + cq * 4;
    const size_t grow1 = ((size_t)bh * SDIM + qt * 64 + rl1) * SDIM + kh * KHALF + cq * 4;
    const float* prow0 = prev + grow0;
    const float* prow1 = prev + grow1;
    float* srow0 = scores + grow0;
    float* srow1 = scores + grow1;

    // K staging identity: thread stages 16B chunks tid and tid+256 of 8KB tile
    const int c0 = tid ^ ((tid >> 3) & 7);            // swizzled dest chunk
    const int c1 = (tid + 256) ^ (((tid + 256) >> 3) & 7);

    f32x4 oacc[4] = {};
    float l0 = 0.0f, l1 = 0.0f;

    // ---- prologue: stage K tile 0; prefetch prev tile 0 ----
    {
        u32x4 kg0 = *(const u32x4*)(kbase + tid * 8);
        u32x4 kg1 = *(const u32x4*)(kbase + (tid + 256) * 8);
        *(u32x4*)&ksmem[c0 * 8] = kg0;
        *(u32x4*)&ksmem[c1 * 8] = kg1;
    }
    f32x4 pf00 = __builtin_nontemporal_load((const f32x4*)(prow0));
    f32x4 pf01 = __builtin_nontemporal_load((const f32x4*)(prow0 + 32));
    f32x4 pf10 = __builtin_nontemporal_load((const f32x4*)(prow1));
    f32x4 pf11 = __builtin_nontemporal_load((const f32x4*)(prow1 + 32));
    __syncthreads();

    for (int tt = 0; tt < 16; ++tt) {
        const int t0  = tt * 64;
        const bool more = tt < 15;

        // ---- B: issue V loads for THIS tile (consumed at PV) ----
        bf16x8 vf[8];
#pragma unroll
        for (int nc = 0; nc < 4; ++nc)
#pragma unroll
            for (int kc = 0; kc < 2; ++kc)
                vf[nc * 2 + kc] = *(const bf16x8*)(vbase + (size_t)nc * 16 * SDIM + (t0 + kc * 32));

        // ---- A: issue next K tile's global loads ----
        u32x4 kg0, kg1;
        if (more) {
            const unsigned short* ktn = kbase + (size_t)(t0 + 64) * DDIM;
            kg0 = *(const u32x4*)(ktn + tid * 8);
            kg1 = *(const u32x4*)(ktn + (tid + 256) * 8);
        }
        // ---- C: issue next prev tile ----
        f32x4 pn00, pn01, pn10, pn11;
        if (more) {
            pn00 = __builtin_nontemporal_load((const f32x4*)(prow0 + t0 + 64));
            pn01 = __builtin_nontemporal_load((const f32x4*)(prow0 + t0 + 96));
            pn10 = __builtin_nontemporal_load((const f32x4*)(prow1 + t0 + 64));
            pn11 = __builtin_nontemporal_load((const f32x4*)(prow1 + t0 + 96));
        }

        // ---- D: S = Q @ K^T from LDS-staged K (swizzled reads) ----
        f32x4 sacc[4] = {};
        __builtin_amdgcn_s_setprio(1);
#pragma unroll
        for (int nc = 0; nc < 4; ++nc) {
            const int trow = nc * 16 + ln;
            const int sw = trow & 7;
#pragma unroll
            for (int kc = 0; kc < 2; ++kc) {
                bf16x8 bf = *(const bf16x8*)&ksmem[trow * 64 + ((kc * 4 + lg) ^ sw) * 8];
                sacc[nc] = __builtin_amdgcn_mfma_f32_16x16x32_bf16(qf[kc], bf, sacc[nc], 0, 0, 0);
            }
        }
        __builtin_amdgcn_s_setprio(0);

        // ---- E: raw barrier — all waves done reading ksmem (reads already
        // consumed by MFMA lgkmcnt deps; no vmcnt drain) ----
        asm volatile("" ::: "memory");
        __builtin_amdgcn_s_barrier();
        asm volatile("" ::: "memory");

        // ---- F: commit next K tile to ksmem ----
        if (more) {
            *(u32x4*)&ksmem[c0 * 8] = kg0;
            *(u32x4*)&ksmem[c1 * 8] = kg1;
        }
        // ---- G: lgkmcnt(0) + raw barrier — ksmem writes visible to all ----
        asm volatile("s_waitcnt lgkmcnt(0)" ::: "memory");
        __builtin_amdgcn_s_barrier();
        asm volatile("" ::: "memory");

        // ---- E1: S to LDS (fragment -> row layout), intra-wave rows ----
#pragma unroll
        for (int nc = 0; nc < 4; ++nc)
#pragma unroll
            for (int r = 0; r < 4; ++r)
                s_lds[wave * 16 + lg * 4 + r][nc * 16 + ln] = sacc[nc][r];

        // ---- E2: row layout — scale + prev, store scores, exp, pack P ----
        f32x4 s00 = *(const f32x4*)&s_lds[rl0][cq * 4];
        f32x4 s01 = *(const f32x4*)&s_lds[rl0][32 + cq * 4];
        f32x4 s10 = *(const f32x4*)&s_lds[rl1][cq * 4];
        f32x4 s11 = *(const f32x4*)&s_lds[rl1][32 + cq * 4];
        s00 = s00 * 0.125f + pf00;
        s01 = s01 * 0.125f + pf01;
        s10 = s10 * 0.125f + pf10;
        s11 = s11 * 0.125f + pf11;
        __builtin_nontemporal_store(s00, (f32x4*)(srow0 + t0));
        __builtin_nontemporal_store(s01, (f32x4*)(srow0 + t0 + 32));
        __builtin_nontemporal_store(s10, (f32x4*)(srow1 + t0));
        __builtin_nontemporal_store(s11, (f32x4*)(srow1 + t0 + 32));

        f32x4 p00, p01, p10, p11;
        p00.x = __expf(s00.x); p00.y = __expf(s00.y);
        p00.z = __expf(s00.z); p00.w = __expf(s00.w);
        p01.x = __expf(s01.x); p01.y = __expf(s01.y);
        p01.z = __expf(s01.z); p01.w = __expf(s01.w);
        p10.x = __expf(s10.x); p10.y = __expf(s10.y);
        p10.z = __expf(s10.z); p10.w = __expf(s10.w);
        p11.x = __expf(s11.x); p11.y = __expf(s11.y);
        p11.z = __expf(s11.z); p11.w = __expf(s11.w);

        l0 += (p00.x + p00.y + p00.z + p00.w) + (p01.x + p01.y + p01.z + p01.w);
        l1 += (p10.x + p10.y + p10.z + p10.w) + (p11.x + p11.y + p11.z + p11.w);

        // packed P (bf16 pairs as float bit patterns) into s_lds cols 0..31
        {
            f32x2 w;
            w.x = asf(packbf(p00.x, p00.y)); w.y = asf(packbf(p00.z, p00.w));
            *(f32x2*)&s_lds[rl0][cq * 2] = w;
            w.x = asf(packbf(p01.x, p01.y)); w.y = asf(packbf(p01.z, p01.w));
            *(f32x2*)&s_lds[rl0][16 + cq * 2] = w;
            w.x = asf(packbf(p10.x, p10.y)); w.y = asf(packbf(p10.z, p10.w));
            *(f32x2*)&s_lds[rl1][cq * 2] = w;
            w.x = asf(packbf(p11.x, p11.y)); w.y = asf(packbf(p11.z, p11.w));
            *(f32x2*)&s_lds[rl1][16 + cq * 2] = w;
        }

        // ---- PV: fragment layout — O += P @ V ----
        bf16x8 pa[2];
#pragma unroll
        for (int kc = 0; kc < 2; ++kc) {
            f32x4 praw = *(const f32x4*)&s_lds[wave * 16 + ln][kc * 16 + lg * 4];
            pa[kc] = *(const bf16x8*)&praw;
        }
        __builtin_amdgcn_s_setprio(1);
#pragma unroll
        for (int nc = 0; nc < 4; ++nc)
#pragma unroll
            for (int kc = 0; kc < 2; ++kc)
                oacc[nc] = __builtin_amdgcn_mfma_f32_16x16x32_bf16(pa[kc], vf[nc * 2 + kc], oacc[nc], 0, 0, 0);
        __builtin_amdgcn_s_setprio(0);

        if (more) { pf00 = pn00; pf01 = pn01; pf10 = pn10; pf11 = pn11; }
    }

    // ---- epilogue: reduce l over 8 col-lanes; store partial O + l ----
    l0 += __shfl_xor(l0, 1, 64);
    l0 += __shfl_xor(l0, 2, 64);
    l0 += __shfl_xor(l0, 4, 64);
    l1 += __shfl_xor(l1, 1, 64);
    l1 += __shfl_xor(l1, 2, 64);
    l1 += __shfl_xor(l1, 4, 64);

#pragma unroll
    for (int nc = 0; nc < 4; ++nc)
#pragma unroll
        for (int r = 0; r < 4; ++r)
            s_lds[wave * 16 + lg * 4 + r][nc * 16 + ln] = oacc[nc][r];

    const int pblk = ((bh * 32 + qt) * 2 + kh);
    float* opb = Opart + (size_t)pblk * 4096;
    if (cq == 0) {
        lpart[(size_t)pblk * 64 + rl0] = l0;
        lpart[(size_t)pblk * 64 + rl1] = l1;
    }
    f32x4 o00 = *(const f32x4*)&s_lds[rl0][cq * 4];
    f32x4 o01 = *(const f32x4*)&s_lds[rl0][32 + cq * 4];
    f32x4 o10 = *(const f32x4*)&s_lds[rl1][cq * 4];
    f32x4 o11 = *(const f32x4*)&s_lds[rl1][32 + cq * 4];
    *(f32x4*)(opb + rl0 * 64 + cq * 4)      = o00;
    *(f32x4*)(opb + rl0 * 64 + cq * 4 + 32) = o01;
    *(f32x4*)(opb + rl1 * 64 + cq * 4)      = o10;
    *(f32x4*)(opb + rl1 * 64 + cq * 4 + 32) = o11;
}

// combine: out = (Oa + Ob) / (la + lb), per (bh, qt) tile of 64x64
__global__ __launch_bounds__(256) void combine_halves(
    const float* __restrict__ Opart, const float* __restrict__ lpart,
    float* __restrict__ out)
{
    const int idx = blockIdx.x;            // bh*32 + qt
    const int bh = idx >> 5, qt = idx & 31;
    const int row = threadIdx.x >> 2;      // 0..63
    const int cb  = (threadIdx.x & 3) * 16;
    const size_t pa = ((size_t)idx * 2) * 4096 + row * 64 + cb;
    const size_t pb = pa + 4096;
    const float la = lpart[(size_t)(idx * 2) * 64 + row];
    const float lb = lpart[(size_t)(idx * 2 + 1) * 64 + row];
    const float inv = 1.0f / (la + lb);
    float* o = out + ((size_t)bh * SDIM + qt * 64 + row) * DDIM + cb;
#pragma unroll
    for (int j = 0; j < 4; ++j) {
        f32x4 a = *(const f32x4*)(Opart + pa + j * 4);
        f32x4 b = *(const f32x4*)(Opart + pb + j * 4);
        *(f32x4*)(o + j * 4) = (a + b) * inv;
    }
}

extern "C" void kernel_launch(void* const* d_in, const int* in_sizes, int n_in,
                              void* d_out, int out_size, void* d_ws, size_t ws_size,
                              hipStream_t stream) {
    const float* q    = (const float*)d_in[0];
    const float* k    = (const float*)d_in[1];
    const float* v    = (const float*)d_in[2];
    const float* prev = (const float*)d_in[3];

    float* out    = (float*)d_out;
    float* scores = out + (size_t)NBH * SDIM * DDIM;   // outputs concatenated

    unsigned short* kT = (unsigned short*)d_ws;                 // 8 MB
    unsigned short* vT = kT + (size_t)NBH * SDIM * DDIM;        // 8 MB
    float* Opart = (float*)(vT + (size_t)NBH * SDIM * DDIM);    // 32 MB
    float* lpart = Opart + (size_t)2048 * 4096;                 // 512 KB

    // k: [bh][64][2048] -> kT [bh][2048][64]
    transpose_cvt<<<dim3(SDIM / 64, 1, NBH), 256, 0, stream>>>(k, kT, DDIM, SDIM);
    // v: [bh][2048][64] -> vT [bh][64][2048]
    transpose_cvt<<<dim3(1, SDIM / 64, NBH), 256, 0, stream>>>(v, vT, SDIM, DDIM);

    attn_partial<<<dim3(SDIM / 64, 2, NBH), 256, 0, stream>>>(
        q, prev, kT, vT, Opart, lpart, scores);
    combine_halves<<<dim3(NBH * 32), 256, 0, stream>>>(Opart, lpart, out);
}

// Round 13
// 308.619 us; speedup vs baseline: 3.0386x; 3.0386x over previous
//
#include <hip/hip_runtime.h>

typedef __attribute__((ext_vector_type(8))) short bf16x8;
typedef __attribute__((ext_vector_type(4))) float f32x4;
typedef __attribute__((ext_vector_type(2))) float f32x2;
typedef __attribute__((ext_vector_type(4))) unsigned int u32x4;

#define SDIM 2048
#define DDIM 64
#define NBH  32

__device__ __forceinline__ unsigned short f2bf(float f) {
    union { float f; unsigned int u; } x;
    x.f = f;
    unsigned int u = x.u;
    u += 0x7FFFu + ((u >> 16) & 1u);  // round-to-nearest-even
    return (unsigned short)(u >> 16);
}

__device__ __forceinline__ unsigned int packbf(float a, float b) {
    return (unsigned int)f2bf(a) | ((unsigned int)f2bf(b) << 16);
}

__device__ __forceinline__ float asf(unsigned int u) {
    union { unsigned int u; float f; } x; x.u = u; return x.f;
}

// transpose [bh][R][C] f32 -> [bh][C][R] bf16(ushort), 64x64 tiles via LDS
__global__ __launch_bounds__(256) void transpose_cvt(
    const float* __restrict__ in, unsigned short* __restrict__ out,
    int R, int C)
{
    __shared__ float tile[64][65];
    const int bh = blockIdx.z;
    const int ct = blockIdx.x * 64;
    const int rt = blockIdx.y * 64;
    const float* src = in + (size_t)bh * R * C;
    unsigned short* dst = out + (size_t)bh * R * C;
    const int r = threadIdx.x >> 2;   // 0..63
    const int p = threadIdx.x & 3;    // 0..3
    const float* sp = src + (size_t)(rt + r) * C + ct + p * 16;
#pragma unroll
    for (int j = 0; j < 4; ++j) {
        f32x4 a = *(const f32x4*)(sp + j * 4);
        tile[r][p*16 + j*4 + 0] = a.x;
        tile[r][p*16 + j*4 + 1] = a.y;
        tile[r][p*16 + j*4 + 2] = a.z;
        tile[r][p*16 + j*4 + 3] = a.w;
    }
    __syncthreads();
    u32x4 w0, w1;
    w0.x = packbf(tile[p*16+ 0][r], tile[p*16+ 1][r]);
    w0.y = packbf(tile[p*16+ 2][r], tile[p*16+ 3][r]);
    w0.z = packbf(tile[p*16+ 4][r], tile[p*16+ 5][r]);
    w0.w = packbf(tile[p*16+ 6][r], tile[p*16+ 7][r]);
    w1.x = packbf(tile[p*16+ 8][r], tile[p*16+ 9][r]);
    w1.y = packbf(tile[p*16+10][r], tile[p*16+11][r]);
    w1.z = packbf(tile[p*16+12][r], tile[p*16+13][r]);
    w1.w = packbf(tile[p*16+14][r], tile[p*16+15][r]);
    unsigned short* dp = dst + (size_t)(ct + r) * R + rt + p * 16;
    *(u32x4*)dp = w0;
    *(u32x4*)(dp + 8) = w1;
}

// Fused attention, no-max softmax, deep-issue pipeline (= R8 schedule) with
// LDS shrunk to 25.6KB for 6 blocks/CU: the 64x64 f32 S-exchange runs as
// TWO intra-wave passes through a [64][36] buffer (cols 0-31, then 32-63).
// Same-wave DS ops are in-order -> no barriers for the exchange. K tile
// double-buffered in LDS (global issue at top, ds_write at bottom,
// XOR-swizzled). prev prefetched 1 tile ahead, nt hints (R9: L2 routing
// hurt). One __syncthreads per iteration.
__global__ __launch_bounds__(256, 4) void attn_fused(
    const float* __restrict__ q, const float* __restrict__ prev,
    const unsigned short* __restrict__ kT, const unsigned short* __restrict__ vT,
    float* __restrict__ out, float* __restrict__ scores)
{
    const int bh   = blockIdx.y;
    const int qt   = blockIdx.x;          // 64-row Q tile index
    const int tid  = threadIdx.x;
    const int wave = tid >> 6;
    const int lane = tid & 63;
    const int ln   = lane & 15;           // 0..15
    const int lg   = lane >> 4;           // 0..3

    __shared__ float s_lds[64][36];            // S/P/O exchange, two-pass
    __shared__ unsigned short ksmem[2][4096];  // K tile double buffer (swizzled)

    // ---- Q fragments (A operand: row = ln, k(d) = kc*32 + lg*8 + j) ----
    const int qrow_frag = qt * 64 + wave * 16 + ln;
    bf16x8 qf[2];
    {
        const float* qp = q + ((size_t)bh * SDIM + qrow_frag) * DDIM + lg * 8;
#pragma unroll
        for (int kc = 0; kc < 2; ++kc) {
            f32x4 a = *(const f32x4*)(qp + kc * 32);
            f32x4 b = *(const f32x4*)(qp + kc * 32 + 4);
            bf16x8 f;
            f[0] = (short)f2bf(a.x); f[1] = (short)f2bf(a.y);
            f[2] = (short)f2bf(a.z); f[3] = (short)f2bf(a.w);
            f[4] = (short)f2bf(b.x); f[5] = (short)f2bf(b.y);
            f[6] = (short)f2bf(b.z); f[7] = (short)f2bf(b.w);
            qf[kc] = f;
        }
    }

    const unsigned short* kbh   = kT + (size_t)bh * SDIM * DDIM;
    const unsigned short* vbase = vT + ((size_t)bh * DDIM + ln) * SDIM + lg * 8;

    // ---- row-layout identity: 8 lanes per row, 2 row groups ----
    const int rsub = lane >> 3;           // 0..7
    const int cq   = lane & 7;            // col octet: floats cq*4..cq*4+3
    const int rl0  = wave * 16 + rsub;    // block-local rows
    const int rl1  = rl0 + 8;
    const size_t grow0 = ((size_t)bh * SDIM + qt * 64 + rl0) * SDIM + cq * 4;
    const size_t grow1 = ((size_t)bh * SDIM + qt * 64 + rl1) * SDIM + cq * 4;
    const float* prow0 = prev + grow0;
    const float* prow1 = prev + grow1;
    float* srow0 = scores + grow0;
    float* srow1 = scores + grow1;

    // K staging identity: thread stages 16B chunks tid and tid+256 of 8KB tile
    const int c0 = tid ^ ((tid >> 3) & 7);            // swizzled dest chunk
    const int c1 = (tid + 256) ^ (((tid + 256) >> 3) & 7);

    f32x4 oacc[4] = {};
    float l0 = 0.0f, l1 = 0.0f;           // per-thread partial denominators

    // ---- prologue: stage K tile 0 into buf 0; prefetch prev tile 0 ----
    {
        u32x4 kg0 = *(const u32x4*)(kbh + tid * 8);
        u32x4 kg1 = *(const u32x4*)(kbh + (tid + 256) * 8);
        *(u32x4*)&ksmem[0][c0 * 8] = kg0;
        *(u32x4*)&ksmem[0][c1 * 8] = kg1;
    }
    f32x4 pf00 = __builtin_nontemporal_load((const f32x4*)(prow0));
    f32x4 pf01 = __builtin_nontemporal_load((const f32x4*)(prow0 + 32));
    f32x4 pf10 = __builtin_nontemporal_load((const f32x4*)(prow1));
    f32x4 pf11 = __builtin_nontemporal_load((const f32x4*)(prow1 + 32));
    __syncthreads();

    for (int tt = 0; tt < 32; ++tt) {
        const int t0  = tt * 64;
        const int buf = tt & 1;
        const bool more = tt < 31;

        // ---- B: issue V loads for THIS tile (consumed at F) ----
        bf16x8 vf[8];
#pragma unroll
        for (int nc = 0; nc < 4; ++nc)
#pragma unroll
            for (int kc = 0; kc < 2; ++kc)
                vf[nc * 2 + kc] = *(const bf16x8*)(vbase + (size_t)nc * 16 * SDIM + (t0 + kc * 32));

        // ---- A: issue next K tile's global loads (consumed at G) ----
        u32x4 kg0, kg1;
        if (more) {
            const unsigned short* ktn = kbh + (size_t)(t0 + 64) * DDIM;
            kg0 = *(const u32x4*)(ktn + tid * 8);
            kg1 = *(const u32x4*)(ktn + (tid + 256) * 8);
        }
        // ---- C: issue next prev tile ----
        f32x4 pn00, pn01, pn10, pn11;
        if (more) {
            pn00 = __builtin_nontemporal_load((const f32x4*)(prow0 + t0 + 64));
            pn01 = __builtin_nontemporal_load((const f32x4*)(prow0 + t0 + 96));
            pn10 = __builtin_nontemporal_load((const f32x4*)(prow1 + t0 + 64));
            pn11 = __builtin_nontemporal_load((const f32x4*)(prow1 + t0 + 96));
        }

        // ---- D: S = Q @ K^T from LDS-staged K (swizzled reads) ----
        f32x4 sacc[4] = {};
        __builtin_amdgcn_s_setprio(1);
#pragma unroll
        for (int nc = 0; nc < 4; ++nc) {
            const int trow = nc * 16 + ln;
            const int sw = trow & 7;
#pragma unroll
            for (int kc = 0; kc < 2; ++kc) {
                bf16x8 bf = *(const bf16x8*)&ksmem[buf][trow * 64 + ((kc * 4 + lg) ^ sw) * 8];
                sacc[nc] = __builtin_amdgcn_mfma_f32_16x16x32_bf16(qf[kc], bf, sacc[nc], 0, 0, 0);
            }
        }
        __builtin_amdgcn_s_setprio(0);

        // ---- E: S exchange, two intra-wave passes through [64][36] ----
        // pass 1: cols 0..31
#pragma unroll
        for (int nc = 0; nc < 2; ++nc)
#pragma unroll
            for (int r = 0; r < 4; ++r)
                s_lds[wave * 16 + lg * 4 + r][nc * 16 + ln] = sacc[nc][r];
        f32x4 s00 = *(const f32x4*)&s_lds[rl0][cq * 4];
        f32x4 s10 = *(const f32x4*)&s_lds[rl1][cq * 4];
        // pass 2: cols 32..63 (reuse same physical cols)
#pragma unroll
        for (int nc = 2; nc < 4; ++nc)
#pragma unroll
            for (int r = 0; r < 4; ++r)
                s_lds[wave * 16 + lg * 4 + r][(nc - 2) * 16 + ln] = sacc[nc][r];
        f32x4 s01 = *(const f32x4*)&s_lds[rl0][cq * 4];
        f32x4 s11 = *(const f32x4*)&s_lds[rl1][cq * 4];

        // ---- row layout: scale + prev, store scores (full 128B lines) ----
        s00 = s00 * 0.125f + pf00;
        s01 = s01 * 0.125f + pf01;
        s10 = s10 * 0.125f + pf10;
        s11 = s11 * 0.125f + pf11;
        __builtin_nontemporal_store(s00, (f32x4*)(srow0 + t0));
        __builtin_nontemporal_store(s01, (f32x4*)(srow0 + t0 + 32));
        __builtin_nontemporal_store(s10, (f32x4*)(srow1 + t0));
        __builtin_nontemporal_store(s11, (f32x4*)(srow1 + t0 + 32));

        // ---- no-max softmax numerator ----
        f32x4 p00, p01, p10, p11;
        p00.x = __expf(s00.x); p00.y = __expf(s00.y);
        p00.z = __expf(s00.z); p00.w = __expf(s00.w);
        p01.x = __expf(s01.x); p01.y = __expf(s01.y);
        p01.z = __expf(s01.z); p01.w = __expf(s01.w);
        p10.x = __expf(s10.x); p10.y = __expf(s10.y);
        p10.z = __expf(s10.z); p10.w = __expf(s10.w);
        p11.x = __expf(s11.x); p11.y = __expf(s11.y);
        p11.z = __expf(s11.z); p11.w = __expf(s11.w);

        l0 += (p00.x + p00.y + p00.z + p00.w) + (p01.x + p01.y + p01.z + p01.w);
        l1 += (p10.x + p10.y + p10.z + p10.w) + (p11.x + p11.y + p11.z + p11.w);

        // ---- packed P (bf16 pairs as float bits) into cols 0..31 ----
        {
            f32x2 w;
            w.x = asf(packbf(p00.x, p00.y)); w.y = asf(packbf(p00.z, p00.w));
            *(f32x2*)&s_lds[rl0][cq * 2] = w;
            w.x = asf(packbf(p01.x, p01.y)); w.y = asf(packbf(p01.z, p01.w));
            *(f32x2*)&s_lds[rl0][16 + cq * 2] = w;
            w.x = asf(packbf(p10.x, p10.y)); w.y = asf(packbf(p10.z, p10.w));
            *(f32x2*)&s_lds[rl1][cq * 2] = w;
            w.x = asf(packbf(p11.x, p11.y)); w.y = asf(packbf(p11.z, p11.w));
            *(f32x2*)&s_lds[rl1][16 + cq * 2] = w;
        }

        // ---- F: fragment layout — O += P @ V ----
        bf16x8 pa[2];
#pragma unroll
        for (int kc = 0; kc < 2; ++kc) {
            f32x4 praw = *(const f32x4*)&s_lds[wave * 16 + ln][kc * 16 + lg * 4];
            pa[kc] = *(const bf16x8*)&praw;
        }
        __builtin_amdgcn_s_setprio(1);
#pragma unroll
        for (int nc = 0; nc < 4; ++nc)
#pragma unroll
            for (int kc = 0; kc < 2; ++kc)
                oacc[nc] = __builtin_amdgcn_mfma_f32_16x16x32_bf16(pa[kc], vf[nc * 2 + kc], oacc[nc], 0, 0, 0);
        __builtin_amdgcn_s_setprio(0);

        // ---- G: write staged K regs to next LDS buffer; rotate prev ----
        if (more) {
            *(u32x4*)&ksmem[buf ^ 1][c0 * 8] = kg0;
            *(u32x4*)&ksmem[buf ^ 1][c1 * 8] = kg1;
            pf00 = pn00; pf01 = pn01; pf10 = pn10; pf11 = pn11;
        }
        __syncthreads();
    }

    // ---- epilogue: reduce l over the 8 col-lanes ----
    l0 += __shfl_xor(l0, 1, 64);
    l0 += __shfl_xor(l0, 2, 64);
    l0 += __shfl_xor(l0, 4, 64);
    l1 += __shfl_xor(l1, 1, 64);
    l1 += __shfl_xor(l1, 2, 64);
    l1 += __shfl_xor(l1, 4, 64);
    const float li0 = 1.0f / l0;
    const float li1 = 1.0f / l1;

    // ---- O through LDS, two passes; full-line stores ----
    const size_t ob0 = ((size_t)bh * SDIM + qt * 64 + rl0) * DDIM + cq * 4;
    const size_t ob1 = ((size_t)bh * SDIM + qt * 64 + rl1) * DDIM + cq * 4;
    // pass 1: cols 0..31
#pragma unroll
    for (int nc = 0; nc < 2; ++nc)
#pragma unroll
        for (int r = 0; r < 4; ++r)
            s_lds[wave * 16 + lg * 4 + r][nc * 16 + ln] = oacc[nc][r];
    f32x4 o00 = *(const f32x4*)&s_lds[rl0][cq * 4];
    f32x4 o10 = *(const f32x4*)&s_lds[rl1][cq * 4];
    // pass 2: cols 32..63
#pragma unroll
    for (int nc = 2; nc < 4; ++nc)
#pragma unroll
        for (int r = 0; r < 4; ++r)
            s_lds[wave * 16 + lg * 4 + r][(nc - 2) * 16 + ln] = oacc[nc][r];
    f32x4 o01 = *(const f32x4*)&s_lds[rl0][cq * 4];
    f32x4 o11 = *(const f32x4*)&s_lds[rl1][cq * 4];

    *(f32x4*)(out + ob0)      = o00 * li0;
    *(f32x4*)(out + ob0 + 32) = o01 * li0;
    *(f32x4*)(out + ob1)      = o10 * li1;
    *(f32x4*)(out + ob1 + 32) = o11 * li1;
}

extern "C" void kernel_launch(void* const* d_in, const int* in_sizes, int n_in,
                              void* d_out, int out_size, void* d_ws, size_t ws_size,
                              hipStream_t stream) {
    const float* q    = (const float*)d_in[0];
    const float* k    = (const float*)d_in[1];
    const float* v    = (const float*)d_in[2];
    const float* prev = (const float*)d_in[3];

    float* out    = (float*)d_out;
    float* scores = out + (size_t)NBH * SDIM * DDIM;   // outputs concatenated

    unsigned short* kT = (unsigned short*)d_ws;                 // [bh][2048][64] bf16
    unsigned short* vT = kT + (size_t)NBH * SDIM * DDIM;        // [bh][64][2048] bf16

    // k: [bh][64][2048] -> kT [bh][2048][64]
    transpose_cvt<<<dim3(SDIM / 64, 1, NBH), 256, 0, stream>>>(k, kT, DDIM, SDIM);
    // v: [bh][2048][64] -> vT [bh][64][2048]
    transpose_cvt<<<dim3(1, SDIM / 64, NBH), 256, 0, stream>>>(v, vT, SDIM, DDIM);

    attn_fused<<<dim3(SDIM / 64, NBH), 256, 0, stream>>>(q, prev, kT, vT, out, scores);
}